// Round 5
// baseline (108.418 us; speedup 1.0000x reference)
//
#include <hip/hip_runtime.h>

// ModulatedDeformConv2d fwd — hybrid design (round 5):
//   xtrans:  x NCHW fp32 -> xT NHWC bf16 (one bilinear neighbor = 128 contiguous B)
//   wtrans2: weight -> wbfA in exact MFMA A-fragment order (16B/lane coalesced)
//   dcn3:    phase 0 = block-coalesced bilinear tables -> 18KB LDS, ONE barrier;
//            then per-wave 16px x 64o tile, bilinear gather lands directly in
//            MFMA B-fragment registers (no S staging in LDS).
// B=4 C=64 H=W=96 O=64 K=3x3 stride=1 pad=1 dil=1 groups=1 dg=1
#define Bn 4
#define Cn 64
#define Hn 96
#define Wn 96
#define On 64
#define Kn 9
#define HWn (Hn*Wn)
#define NT 256
#define TW (Wn/16)          // 6 pixel-tiles per row
#define NTILES (Bn*Hn*TW)   // 2304 waves total
#define NBLK (NTILES/4)     // 576 blocks of 4 waves

typedef __attribute__((ext_vector_type(8))) short bf16x8;
typedef __attribute__((ext_vector_type(4))) float f32x4;

__device__ __forceinline__ unsigned short f2bf(float f) {
    unsigned u = __float_as_uint(f);
    u += 0x7FFFu + ((u >> 16) & 1u);   // RNE; inputs finite
    return (unsigned short)(u >> 16);
}
__device__ __forceinline__ float bf2f(unsigned short h) {
    return __uint_as_float((unsigned)h << 16);
}

// wbfA fragment order: frag (t=K-window 0..17, ot=o-tile 0..3), lane l:
//   A[o = ot*16 + (l&15)][kappa = t*32 + (l>>4)*8 + j], j=0..7, kappa = k*64+c.
__global__ void wtrans2_kernel(const float* __restrict__ w, unsigned short* __restrict__ wbfA) {
    int i = blockIdx.x * NT + threadIdx.x;
    if (i < 18 * 4 * 64 * 8) {
        int j  = i & 7;
        int l  = (i >> 3) & 63;
        int ot = (i >> 9) & 3;
        int t  = i >> 11;
        int o  = ot * 16 + (l & 15);
        int kp = t * 32 + (l >> 4) * 8 + j;
        wbfA[i] = f2bf(w[(o * Cn + (kp & 63)) * Kn + (kp >> 6)]);
    }
}

// xT[b][h][w][c] = bf16(x[b][c][h][w])
__global__ __launch_bounds__(NT) void xtrans_kernel(const float* __restrict__ x,
                                                    unsigned short* __restrict__ xT) {
    __shared__ unsigned short tile[Cn * Wn];   // 12 KB
    const int tid = threadIdx.x;
    const int b = blockIdx.x / Hn;
    const int h = blockIdx.x - b * Hn;
    #pragma unroll
    for (int i = 0; i < (Cn * Wn) / NT; ++i) {
        int e = i * NT + tid;
        int c = e / Wn, w = e - c * Wn;
        tile[c * Wn + w] = f2bf(x[(((size_t)b * Cn + c) * Hn + h) * Wn + w]);
    }
    __syncthreads();
    #pragma unroll
    for (int i = 0; i < (Wn * 8) / NT; ++i) {
        int s = i * NT + tid;
        int w = s >> 3, g = s & 7;
        unsigned short hh[8];
        #pragma unroll
        for (int j = 0; j < 8; ++j) hh[j] = tile[(g * 8 + j) * Wn + w];
        uint4 pk;
        pk.x = hh[0] | ((unsigned)hh[1] << 16);
        pk.y = hh[2] | ((unsigned)hh[3] << 16);
        pk.z = hh[4] | ((unsigned)hh[5] << 16);
        pk.w = hh[6] | ((unsigned)hh[7] << 16);
        *(uint4*)&xT[(((size_t)b * Hn + h) * Wn + w) * Cn + g * 8] = pk;
    }
}

__global__ __launch_bounds__(NT) void dcn3_kernel(
    const unsigned short* __restrict__ xT, const float* __restrict__ offset,
    const float* __restrict__ mask, const float* __restrict__ bias,
    const unsigned short* __restrict__ wbfA, float* __restrict__ out)
{
    __shared__ float4 lwv[4 * Kn * 16];   // 9216 B  (bilinear weights, mask+validity folded)
    __shared__ int4   liv[4 * Kn * 16];   // 9216 B  (clamped flat indices)

    const int tid = threadIdx.x;
    // XCD swizzle: each XCD gets a contiguous 72-block (=48 rows of one batch) span.
    const int p = blockIdx.x;
    const int v = (p & 7) * (NBLK / 8) + (p >> 3);

    // ---- Phase 0: block-coalesced bilinear tables for all 4 waves' tiles
    for (int e = tid; e < 4 * Kn * 16; e += NT) {
        int w   = e / (Kn * 16);
        int r   = e - w * (Kn * 16);
        int k   = r >> 4;
        int n   = r & 15;
        int T   = v * 4 + w;
        int b   = T / (Hn * TW);
        int rem = T - b * (Hn * TW);
        int ho  = rem / TW;
        int wt  = rem - ho * TW;
        int wo  = wt * 16 + n;

        float oy = offset[((b * (2*Kn) + 2*k    ) * Hn + ho) * Wn + wo];
        float ox = offset[((b * (2*Kn) + 2*k + 1) * Hn + ho) * Wn + wo];
        float mm = mask  [((b * Kn + k) * Hn + ho) * Wn + wo];
        float py = (float)(ho - 1 + (k / 3)) + oy;
        float px = (float)(wo - 1 + (k % 3)) + ox;
        float y0f = floorf(py), x0f = floorf(px);
        float ly = py - y0f, lx = px - x0f;
        int y0 = (int)y0f, x0i = (int)x0f;
        int y1 = y0 + 1,   x1i = x0i + 1;
        float vy0 = (y0  >= 0 && y0  < Hn) ? 1.f : 0.f;
        float vy1 = (y1  >= 0 && y1  < Hn) ? 1.f : 0.f;
        float vx0 = (x0i >= 0 && x0i < Wn) ? 1.f : 0.f;
        float vx1 = (x1i >= 0 && x1i < Wn) ? 1.f : 0.f;
        int cy0 = min(max(y0, 0),  Hn-1), cy1 = min(max(y1, 0),  Hn-1);
        int cx0 = min(max(x0i, 0), Wn-1), cx1 = min(max(x1i, 0), Wn-1);
        float4 wv;
        wv.x = (1.f - ly) * (1.f - lx) * mm * vy0 * vx0;
        wv.y = (1.f - ly) * lx         * mm * vy0 * vx1;
        wv.z = ly         * (1.f - lx) * mm * vy1 * vx0;
        wv.w = ly         * lx         * mm * vy1 * vx1;
        lwv[e] = wv;
        liv[e] = make_int4(cy0 * Wn + cx0, cy0 * Wn + cx1,
                           cy1 * Wn + cx0, cy1 * Wn + cx1);
    }
    __syncthreads();

    // ---- Per-wave: 16px x 64o tile; gather -> B fragments in registers -> MFMA
    const int wave = tid >> 6;
    const int lane = tid & 63;
    const int n    = lane & 15;   // pixel within tile (= MFMA col)
    const int quad = lane >> 4;   // k-slice owner
    const int qo   = quad * 8;    // channel octet offset within window

    const int T  = v * 4 + wave;
    const int b  = T / (Hn * TW);
    int rem      = T - b * (Hn * TW);
    const int ho = rem / TW;
    const int wt = rem - ho * TW;
    const int wo0 = wt * 16;

    const unsigned short* xb = xT + (size_t)b * HWn * Cn;
    const bf16x8* Af = (const bf16x8*)wbfA;

    f32x4 acc[4] = {{0.f,0.f,0.f,0.f},{0.f,0.f,0.f,0.f},
                    {0.f,0.f,0.f,0.f},{0.f,0.f,0.f,0.f}};

    #pragma unroll
    for (int k = 0; k < Kn; ++k) {
        const int te = (wave * Kn + k) * 16 + n;
        float4 wv = lwv[te];
        int4   iv = liv[te];

        // gather 4 neighbors x 2 channel-octets (16B coalesced loads)
        const unsigned short* r0 = xb + ((size_t)iv.x << 6) + qo;
        const unsigned short* r1 = xb + ((size_t)iv.y << 6) + qo;
        const unsigned short* r2 = xb + ((size_t)iv.z << 6) + qo;
        const unsigned short* r3 = xb + ((size_t)iv.w << 6) + qo;
        bf16x8 v00 = *(const bf16x8*)r0,  v01 = *(const bf16x8*)(r0 + 32);
        bf16x8 v10 = *(const bf16x8*)r1,  v11 = *(const bf16x8*)(r1 + 32);
        bf16x8 v20 = *(const bf16x8*)r2,  v21 = *(const bf16x8*)(r2 + 32);
        bf16x8 v30 = *(const bf16x8*)r3,  v31 = *(const bf16x8*)(r3 + 32);

        // combine -> two B-fragments (K-windows t=2k, 2k+1) directly in registers
        bf16x8 b0, b1;
        #pragma unroll
        for (int j = 0; j < 8; ++j) {
            float f0 = wv.x * bf2f((unsigned short)v00[j]) + wv.y * bf2f((unsigned short)v10[j])
                     + wv.z * bf2f((unsigned short)v20[j]) + wv.w * bf2f((unsigned short)v30[j]);
            float f1 = wv.x * bf2f((unsigned short)v01[j]) + wv.y * bf2f((unsigned short)v11[j])
                     + wv.z * bf2f((unsigned short)v21[j]) + wv.w * bf2f((unsigned short)v31[j]);
            b0[j] = (short)f2bf(f0);
            b1[j] = (short)f2bf(f1);
        }

        const int t0 = 2 * k, t1 = 2 * k + 1;
        #pragma unroll
        for (int ot = 0; ot < 4; ++ot) {
            bf16x8 a0 = Af[(t0 * 4 + ot) * 64 + lane];
            acc[ot] = __builtin_amdgcn_mfma_f32_16x16x32_bf16(a0, b0, acc[ot], 0, 0, 0);
        }
        #pragma unroll
        for (int ot = 0; ot < 4; ++ot) {
            bf16x8 a1 = Af[(t1 * 4 + ot) * 64 + lane];
            acc[ot] = __builtin_amdgcn_mfma_f32_16x16x32_bf16(a1, b1, acc[ot], 0, 0, 0);
        }
    }

    // Epilogue: C/D layout col=lane&15 (=pixel n), row=quad*4+r within 16-o tile.
    #pragma unroll
    for (int ot = 0; ot < 4; ++ot) {
        #pragma unroll
        for (int r = 0; r < 4; ++r) {
            int o = ot * 16 + quad * 4 + r;
            out[(((size_t)b * On + o) * Hn + ho) * Wn + wo0 + n] = acc[ot][r] + bias[o];
        }
    }
}

// Correct-but-slow fallback (only if workspace is too small; never expected).
__global__ __launch_bounds__(NT) void dcn_fallback_kernel(
    const float* __restrict__ x, const float* __restrict__ offset,
    const float* __restrict__ mask, const float* __restrict__ weight,
    const float* __restrict__ bias, float* __restrict__ out)
{
    int idx = blockIdx.x * NT + threadIdx.x;
    if (idx >= Bn * On * HWn) return;
    int wo = idx % Wn;
    int ho = (idx / Wn) % Hn;
    int o  = (idx / HWn) % On;
    int b  = idx / (On * HWn);
    float s = bias[o];
    for (int k = 0; k < Kn; ++k) {
        float oy = offset[((b * (2*Kn) + 2*k    ) * Hn + ho) * Wn + wo];
        float ox = offset[((b * (2*Kn) + 2*k + 1) * Hn + ho) * Wn + wo];
        float mm = mask  [((b * Kn + k) * Hn + ho) * Wn + wo];
        float py = (float)(ho - 1 + (k / 3)) + oy;
        float px = (float)(wo - 1 + (k % 3)) + ox;
        float y0f = floorf(py), x0f = floorf(px);
        float ly = py - y0f, lx = px - x0f;
        int y0 = (int)y0f, x0i = (int)x0f, y1 = y0 + 1, x1i = x0i + 1;
        float vy0 = (y0  >= 0 && y0  < Hn) ? 1.f : 0.f;
        float vy1 = (y1  >= 0 && y1  < Hn) ? 1.f : 0.f;
        float vx0 = (x0i >= 0 && x0i < Wn) ? 1.f : 0.f;
        float vx1 = (x1i >= 0 && x1i < Wn) ? 1.f : 0.f;
        int cy0 = min(max(y0, 0),  Hn-1), cy1 = min(max(y1, 0),  Hn-1);
        int cx0 = min(max(x0i, 0), Wn-1), cx1 = min(max(x1i, 0), Wn-1);
        float w0 = (1.f-ly)*(1.f-lx)*mm*vy0*vx0, w1 = (1.f-ly)*lx*mm*vy0*vx1;
        float w2 = ly*(1.f-lx)*mm*vy1*vx0,       w3 = ly*lx*mm*vy1*vx1;
        int i0 = cy0*Wn+cx0, i1 = cy0*Wn+cx1, i2 = cy1*Wn+cx0, i3 = cy1*Wn+cx1;
        for (int c = 0; c < Cn; ++c) {
            const float* xp = x + ((size_t)b * Cn + c) * HWn;
            float vv = w0*xp[i0] + w1*xp[i1] + w2*xp[i2] + w3*xp[i3];
            s += vv * weight[(o * Cn + c) * Kn + k];
        }
    }
    out[idx] = s;
}

extern "C" void kernel_launch(void* const* d_in, const int* in_sizes, int n_in,
                              void* d_out, int out_size, void* d_ws, size_t ws_size,
                              hipStream_t stream) {
    const float* x      = (const float*)d_in[0];
    const float* offset = (const float*)d_in[1];
    const float* mask   = (const float*)d_in[2];
    const float* weight = (const float*)d_in[3];
    const float* bias   = (const float*)d_in[4];
    float* out = (float*)d_out;

    const size_t xt_bytes = (size_t)Bn * HWn * Cn * sizeof(unsigned short);   // 4.7 MB
    const size_t w_bytes  = (size_t)18 * 4 * 64 * 8 * sizeof(unsigned short); // 73728 B

    if (ws_size >= xt_bytes + w_bytes) {
        unsigned short* xT   = (unsigned short*)d_ws;
        unsigned short* wbfA = (unsigned short*)((char*)d_ws + xt_bytes);
        wtrans2_kernel<<<(18*4*64*8 + NT - 1) / NT, NT, 0, stream>>>(weight, wbfA);
        xtrans_kernel<<<Bn * Hn, NT, 0, stream>>>(x, xT);
        dcn3_kernel<<<NBLK, NT, 0, stream>>>(xT, offset, mask, bias, wbfA, out);
    } else {
        dcn_fallback_kernel<<<(Bn * On * HWn + NT - 1) / NT, NT, 0, stream>>>(
            x, offset, mask, weight, bias, out);
    }
}

// Round 6
// 91.730 us; speedup vs baseline: 1.1819x; 1.1819x over previous
//
#include <hip/hip_runtime.h>

// ModulatedDeformConv2d fwd — round 6: round-3 structure (coalesced LDS-staged
// gather + MFMA GEMM), occupancy-tuned:
//   TP=16 px/block -> 23.3 KB LDS -> 6 blocks/CU (was 3)
//   gather: 16 thr/px, 2 neighbors each + shfl_xor(8) partial-sum reduction
//   A-fragments pre-packed in exact MFMA order (coalesced), 2-deep prefetch
// B=4 C=64 H=W=96 O=64 K=3x3 stride=1 pad=1 dil=1 groups=1 dg=1
#define Bn 4
#define Cn 64
#define Hn 96
#define Wn 96
#define On 64
#define Kn 9
#define HWn (Hn*Wn)
#define NT 256
#define TP 16               // output pixels per block
#define TW (Wn/TP)          // 6 pixel-tiles per row
#define NBLK (Bn*Hn*TW)     // 2304 blocks
#define SSTRIDE 584         // S row stride in bf16 elems (576 + 8 pad)
#define NWELEM (18*4*64*8)  // 36864 packed A elements

typedef __attribute__((ext_vector_type(8))) short bf16x8;
typedef __attribute__((ext_vector_type(4))) float f32x4;

__device__ __forceinline__ unsigned short f2bf(float f) {
    unsigned u = __float_as_uint(f);
    u += 0x7FFFu + ((u >> 16) & 1u);   // RNE; inputs finite
    return (unsigned short)(u >> 16);
}
__device__ __forceinline__ float bf2f(unsigned short h) {
    return __uint_as_float((unsigned)h << 16);
}

// prep: blocks [0, Bn*Hn)          -> xT[b][h][w][c] = bf16(x[b][c][h][w])
//       blocks [Bn*Hn, Bn*Hn+144)  -> wbfA in MFMA A-fragment order:
//   frag (t=K-window 0..17, wv=wave 0..3), lane l:
//   A[o = wv*16 + (l&15)][kappa = t*32 + (l>>4)*8 + j], j=0..7, kappa=k*64+c.
__global__ __launch_bounds__(NT) void prep_kernel(
    const float* __restrict__ x, const float* __restrict__ w,
    unsigned short* __restrict__ xT, unsigned short* __restrict__ wbfA)
{
    __shared__ unsigned short tile[Cn * Wn];   // 12 KB
    const int tid = threadIdx.x;
    if (blockIdx.x < Bn * Hn) {
        const int b = blockIdx.x / Hn;
        const int h = blockIdx.x - b * Hn;
        #pragma unroll
        for (int i = 0; i < (Cn * Wn) / NT; ++i) {
            int e = i * NT + tid;
            int c = e / Wn, ww = e - c * Wn;
            tile[c * Wn + ww] = f2bf(x[(((size_t)b * Cn + c) * Hn + h) * Wn + ww]);
        }
        __syncthreads();
        #pragma unroll
        for (int i = 0; i < (Wn * 8) / NT; ++i) {
            int s = i * NT + tid;
            int ww = s >> 3, g = s & 7;
            unsigned short hh[8];
            #pragma unroll
            for (int j = 0; j < 8; ++j) hh[j] = tile[(g * 8 + j) * Wn + ww];
            uint4 pk;
            pk.x = hh[0] | ((unsigned)hh[1] << 16);
            pk.y = hh[2] | ((unsigned)hh[3] << 16);
            pk.z = hh[4] | ((unsigned)hh[5] << 16);
            pk.w = hh[6] | ((unsigned)hh[7] << 16);
            *(uint4*)&xT[(((size_t)b * Hn + h) * Wn + ww) * Cn + g * 8] = pk;
        }
    } else {
        int i = (blockIdx.x - Bn * Hn) * NT + tid;
        if (i < NWELEM) {
            int j  = i & 7;
            int l  = (i >> 3) & 63;
            int wv = (i >> 9) & 3;
            int t  = i >> 11;
            int o  = wv * 16 + (l & 15);
            int kp = t * 32 + (l >> 4) * 8 + j;
            wbfA[i] = f2bf(w[(o * Cn + (kp & 63)) * Kn + (kp >> 6)]);
        }
    }
}

__global__ __launch_bounds__(NT, 6) void dcn4_kernel(
    const unsigned short* __restrict__ xT, const float* __restrict__ offset,
    const float* __restrict__ mask, const float* __restrict__ bias,
    const unsigned short* __restrict__ wbfA, float* __restrict__ out)
{
    __shared__ float4 lwv[Kn * TP];                              // 2304 B
    __shared__ int4   liv[Kn * TP];                              // 2304 B
    __shared__ __align__(16) unsigned short Slds[TP * SSTRIDE];  // 18688 B
    // total 23296 B -> 6 blocks/CU

    const int tid = threadIdx.x;
    // XCD swizzle: each XCD owns 288 consecutive tiles = 48 rows of one batch.
    const int p = blockIdx.x;
    const int v = (p & 7) * (NBLK / 8) + (p >> 3);
    const int b  = v / (Hn * TW);
    int rem      = v - b * (Hn * TW);
    const int ho = rem / TW;
    const int wt = rem - ho * TW;
    const int wo0 = wt * TP;

    // ---- Phase 0: bilinear tables (validity & mask folded into weights)
    if (tid < Kn * TP) {
        int k = tid >> 4;
        int n = tid & 15;
        int wo = wo0 + n;
        float oy = offset[((b * (2*Kn) + 2*k    ) * Hn + ho) * Wn + wo];
        float ox = offset[((b * (2*Kn) + 2*k + 1) * Hn + ho) * Wn + wo];
        float mm = mask  [((b * Kn + k) * Hn + ho) * Wn + wo];
        float py = (float)(ho - 1 + (k / 3)) + oy;
        float px = (float)(wo - 1 + (k % 3)) + ox;
        float y0f = floorf(py), x0f = floorf(px);
        float ly = py - y0f, lx = px - x0f;
        int y0 = (int)y0f, x0i = (int)x0f;
        int y1 = y0 + 1,   x1i = x0i + 1;
        float vy0 = (y0  >= 0 && y0  < Hn) ? 1.f : 0.f;
        float vy1 = (y1  >= 0 && y1  < Hn) ? 1.f : 0.f;
        float vx0 = (x0i >= 0 && x0i < Wn) ? 1.f : 0.f;
        float vx1 = (x1i >= 0 && x1i < Wn) ? 1.f : 0.f;
        int cy0 = min(max(y0, 0),  Hn-1), cy1 = min(max(y1, 0),  Hn-1);
        int cx0 = min(max(x0i, 0), Wn-1), cx1 = min(max(x1i, 0), Wn-1);
        float4 wv;
        wv.x = (1.f - ly) * (1.f - lx) * mm * vy0 * vx0;
        wv.y = (1.f - ly) * lx         * mm * vy0 * vx1;
        wv.z = ly         * (1.f - lx) * mm * vy1 * vx0;
        wv.w = ly         * lx         * mm * vy1 * vx1;
        lwv[tid] = wv;
        liv[tid] = make_int4(cy0 * Wn + cx0, cy0 * Wn + cx1,
                             cy1 * Wn + cx0, cy1 * Wn + cx1);
    }
    __syncthreads();

    // ---- Phase 1: coalesced gather. 16 thr/px: octet g, neighbor-pair hf.
    {
        const int px = tid >> 4;          // pixel 0..15
        const int g  = tid & 7;           // channel octet
        const int hf = (tid >> 3) & 1;    // 0: neighbors (y0x0,y0x1); 1: (y1x0,y1x1)
        const unsigned short* xb = xT + (size_t)b * HWn * Cn + g * 8;
        #pragma unroll
        for (int k = 0; k < Kn; ++k) {
            const int e = k * TP + px;
            float4 wv = lwv[e];
            int4   iv = liv[e];
            int   ia = hf ? iv.z : iv.x;
            int   ib = hf ? iv.w : iv.y;
            float wa = hf ? wv.z : wv.x;
            float wb = hf ? wv.w : wv.y;
            bf16x8 va = *(const bf16x8*)(xb + ((size_t)ia << 6));
            bf16x8 vb = *(const bf16x8*)(xb + ((size_t)ib << 6));
            unsigned short hh[8];
            #pragma unroll
            for (int j = 0; j < 8; ++j) {
                float f = wa * bf2f((unsigned short)va[j]) + wb * bf2f((unsigned short)vb[j]);
                f += __shfl_xor(f, 8);    // combine the two neighbor-pairs
                hh[j] = f2bf(f);
            }
            if (hf == 0) {
                uint4 pk;
                pk.x = hh[0] | ((unsigned)hh[1] << 16);
                pk.y = hh[2] | ((unsigned)hh[3] << 16);
                pk.z = hh[4] | ((unsigned)hh[5] << 16);
                pk.w = hh[6] | ((unsigned)hh[7] << 16);
                *(uint4*)&Slds[px * SSTRIDE + k * 64 + g * 8] = pk;
            }
        }
    }

    // ---- A prefetch (independent of the barrier)
    const int wave = tid >> 6;
    const int lane = tid & 63;
    const int n    = lane & 15;
    const int quad = lane >> 4;
    const bf16x8* Af = (const bf16x8*)wbfA;
    bf16x8 aCur = Af[(0 * 4 + wave) * 64 + lane];
    bf16x8 aNxt = Af[(1 * 4 + wave) * 64 + lane];
    __syncthreads();

    // ---- Phase 2: GEMM. Wave w -> o-rows [16w,16w+16) x 16 px, K=576.
    f32x4 acc = {0.f, 0.f, 0.f, 0.f};
    #pragma unroll
    for (int t = 0; t < 18; ++t) {
        bf16x8 aUse = aCur;
        aCur = aNxt;
        if (t < 16) aNxt = Af[((t + 2) * 4 + wave) * 64 + lane];
        bf16x8 bfr = *(const bf16x8*)&Slds[n * SSTRIDE + t * 32 + quad * 8];
        acc = __builtin_amdgcn_mfma_f32_16x16x32_bf16(aUse, bfr, acc, 0, 0, 0);
    }

    // ---- Epilogue: C/D layout col=lane&15 (=pixel), row=quad*4+r.
    #pragma unroll
    for (int r = 0; r < 4; ++r) {
        int o = wave * 16 + quad * 4 + r;
        out[(((size_t)b * On + o) * Hn + ho) * Wn + wo0 + n] = acc[r] + bias[o];
    }
}

// Correct-but-slow fallback (only if workspace is too small; never expected).
__global__ __launch_bounds__(NT) void dcn_fallback_kernel(
    const float* __restrict__ x, const float* __restrict__ offset,
    const float* __restrict__ mask, const float* __restrict__ weight,
    const float* __restrict__ bias, float* __restrict__ out)
{
    int idx = blockIdx.x * NT + threadIdx.x;
    if (idx >= Bn * On * HWn) return;
    int wo = idx % Wn;
    int ho = (idx / Wn) % Hn;
    int o  = (idx / HWn) % On;
    int b  = idx / (On * HWn);
    float s = bias[o];
    for (int k = 0; k < Kn; ++k) {
        float oy = offset[((b * (2*Kn) + 2*k    ) * Hn + ho) * Wn + wo];
        float ox = offset[((b * (2*Kn) + 2*k + 1) * Hn + ho) * Wn + wo];
        float mm = mask  [((b * Kn + k) * Hn + ho) * Wn + wo];
        float py = (float)(ho - 1 + (k / 3)) + oy;
        float px = (float)(wo - 1 + (k % 3)) + ox;
        float y0f = floorf(py), x0f = floorf(px);
        float ly = py - y0f, lx = px - x0f;
        int y0 = (int)y0f, x0i = (int)x0f, y1 = y0 + 1, x1i = x0i + 1;
        float vy0 = (y0  >= 0 && y0  < Hn) ? 1.f : 0.f;
        float vy1 = (y1  >= 0 && y1  < Hn) ? 1.f : 0.f;
        float vx0 = (x0i >= 0 && x0i < Wn) ? 1.f : 0.f;
        float vx1 = (x1i >= 0 && x1i < Wn) ? 1.f : 0.f;
        int cy0 = min(max(y0, 0),  Hn-1), cy1 = min(max(y1, 0),  Hn-1);
        int cx0 = min(max(x0i, 0), Wn-1), cx1 = min(max(x1i, 0), Wn-1);
        float w0 = (1.f-ly)*(1.f-lx)*mm*vy0*vx0, w1 = (1.f-ly)*lx*mm*vy0*vx1;
        float w2 = ly*(1.f-lx)*mm*vy1*vx0,       w3 = ly*lx*mm*vy1*vx1;
        int i0 = cy0*Wn+cx0, i1 = cy0*Wn+cx1, i2 = cy1*Wn+cx0, i3 = cy1*Wn+cx1;
        for (int c = 0; c < Cn; ++c) {
            const float* xp = x + ((size_t)b * Cn + c) * HWn;
            float vv = w0*xp[i0] + w1*xp[i1] + w2*xp[i2] + w3*xp[i3];
            s += vv * weight[(o * Cn + c) * Kn + k];
        }
    }
    out[idx] = s;
}

extern "C" void kernel_launch(void* const* d_in, const int* in_sizes, int n_in,
                              void* d_out, int out_size, void* d_ws, size_t ws_size,
                              hipStream_t stream) {
    const float* x      = (const float*)d_in[0];
    const float* offset = (const float*)d_in[1];
    const float* mask   = (const float*)d_in[2];
    const float* weight = (const float*)d_in[3];
    const float* bias   = (const float*)d_in[4];
    float* out = (float*)d_out;

    const size_t xt_bytes = (size_t)Bn * HWn * Cn * sizeof(unsigned short);   // 4.7 MB
    const size_t w_bytes  = (size_t)NWELEM * sizeof(unsigned short);          // 73728 B

    if (ws_size >= xt_bytes + w_bytes) {
        unsigned short* xT   = (unsigned short*)d_ws;
        unsigned short* wbfA = (unsigned short*)((char*)d_ws + xt_bytes);
        prep_kernel<<<Bn * Hn + (NWELEM + NT - 1) / NT, NT, 0, stream>>>(x, weight, xT, wbfA);
        dcn4_kernel<<<NBLK, NT, 0, stream>>>(xT, offset, mask, bias, wbfA, out);
    } else {
        dcn_fallback_kernel<<<(Bn * On * HWn + NT - 1) / NT, NT, 0, stream>>>(
            x, offset, mask, weight, bias, out);
    }
}